// Round 1
// 8421.496 us; speedup vs baseline: 1.6727x; 1.6727x over previous
//
#include <hip/hip_runtime.h>
#include <math.h>

// Problem constants
#define BB   16
#define SS   256
#define NV   196
#define DD   768
#define FFD  2048
#define VV   30522
#define NL   6
#define NHH  8
#define HDD  96

typedef __attribute__((ext_vector_type(8))) short short8;
typedef __attribute__((ext_vector_type(4))) float f32x4;

// ---------------- block reductions (blockDim.x == 256 -> 4 waves) ----------------
__device__ __forceinline__ float blockSum(float v, float* red) {
  int lane = threadIdx.x & 63, w = threadIdx.x >> 6;
  #pragma unroll
  for (int o = 32; o; o >>= 1) v += __shfl_down(v, o);
  __syncthreads();
  if (lane == 0) red[w] = v;
  __syncthreads();
  return red[0] + red[1] + red[2] + red[3];
}

__device__ __forceinline__ float blockMax(float v, float* red) {
  int lane = threadIdx.x & 63, w = threadIdx.x >> 6;
  #pragma unroll
  for (int o = 32; o; o >>= 1) v = fmaxf(v, __shfl_down(v, o));
  __syncthreads();
  if (lane == 0) red[w] = v;
  __syncthreads();
  return fmaxf(fmaxf(red[0], red[1]), fmaxf(red[2], red[3]));
}

// ---------------- generic batched GEMM (fp32 VALU path, kept for small attention GEMMs)
__global__ __launch_bounds__(256) void gemm_k(
    const float* __restrict__ A, int lda, long long bsAb, long long bsAh,
    const float* __restrict__ Bm, int ldb, long long bsBb, long long bsBh, int transB,
    float* __restrict__ C, int ldc, long long bsCb, long long bsCh,
    const float* __restrict__ bias,
    int M, int N, int K, float alpha, int relu, int remapA, int nInner)
{
  int z = blockIdx.z;
  int zb = z / nInner, zh = z - zb * nInner;
  A  += zb * bsAb + zh * bsAh;
  Bm += zb * bsBb + zh * bsBh;
  C  += zb * bsCb + zh * bsCh;

  const int bm = blockIdx.y << 6, bn = blockIdx.x << 6;
  const int tid = threadIdx.x;
  const int tx = tid & 15, ty = tid >> 4;

  __shared__ __align__(16) float As[16][68];
  __shared__ __align__(16) float Bs[16][68];

  const float* aptr[4]; bool aval[4];
  {
    int lm0 = tid >> 4;
    #pragma unroll
    for (int p = 0; p < 4; ++p) {
      int gr = bm + lm0 + p * 16;
      aval[p] = gr < M;
      int ar = gr;
      if (remapA) { int bq = gr / 255; ar = bq * 256 + (gr - bq * 255); }
      aptr[p] = A + (long long)ar * lda;
    }
  }
  const float* bptr[4]; bool bval[4];
  if (!transB) {
    int ln0 = tid >> 4;
    #pragma unroll
    for (int p = 0; p < 4; ++p) {
      int gn = bn + ln0 + p * 16;
      bval[p] = gn < N;
      bptr[p] = Bm + (long long)gn * ldb;
    }
  }

  float acc[4][4] = {{0.f}};

  for (int k0 = 0; k0 < K; k0 += 16) {
    int lk = tid & 15;
    int gk = k0 + lk;
    bool kok = gk < K;
    {
      int lm0 = tid >> 4;
      #pragma unroll
      for (int p = 0; p < 4; ++p) {
        float v = 0.f;
        if (aval[p] && kok) v = aptr[p][gk];
        As[lk][lm0 + p * 16] = v;
      }
    }
    if (!transB) {
      int ln0 = tid >> 4;
      #pragma unroll
      for (int p = 0; p < 4; ++p) {
        float v = 0.f;
        if (bval[p] && kok) v = bptr[p][gk];
        Bs[lk][ln0 + p * 16] = v;
      }
    } else {
      int ln = tid & 63;
      int lk0 = tid >> 6;
      int gn = bn + ln;
      #pragma unroll
      for (int p = 0; p < 4; ++p) {
        int kk = lk0 + p * 4;
        int gkk = k0 + kk;
        float v = 0.f;
        if (gn < N && gkk < K) v = Bm[(long long)gkk * ldb + gn];
        Bs[kk][ln] = v;
      }
    }
    __syncthreads();
    #pragma unroll
    for (int kk = 0; kk < 16; ++kk) {
      float4 av = *(const float4*)&As[kk][ty << 2];
      float4 bv = *(const float4*)&Bs[kk][tx << 2];
      float a_[4] = {av.x, av.y, av.z, av.w};
      float b_[4] = {bv.x, bv.y, bv.z, bv.w};
      #pragma unroll
      for (int i = 0; i < 4; ++i)
        #pragma unroll
        for (int j = 0; j < 4; ++j)
          acc[i][j] += a_[i] * b_[j];
    }
    __syncthreads();
  }

  #pragma unroll
  for (int i = 0; i < 4; ++i) {
    int gr = bm + (ty << 2) + i;
    if (gr >= M) continue;
    float* crow = C + (long long)gr * ldc;
    #pragma unroll
    for (int j = 0; j < 4; ++j) {
      int gc = bn + (tx << 2) + j;
      if (gc >= N) continue;
      float v = acc[i][j] * alpha;
      if (bias) v += bias[gc];
      if (relu) v = fmaxf(v, 0.f);
      crow[gc] = v;
    }
  }
}

// ---------------- split-bf16 MFMA GEMM: C = A @ B^T + bias (+relu) ----------------
// fp32 inputs decomposed on the fly: a = hi(bf16) + lo(bf16); acc = AhBh + AhBl + AlBh.
// A: (M,K) row-major lda (remapA: logical row r -> physical (r/255)*256 + r%255)
// B: (N,K) row-major ldb (weights). C: (M,N) row-major ldc. K % 32 == 0.
// Tile 128x128, BK=32, 4 waves (2x2), 64x64 per wave, 16x16x32 MFMA.
// LDS row stride 40 shorts (80B): 16B-aligned, 2-way bank alias only (free).
#define LSTR 40

__global__ __launch_bounds__(256, 2) void gemm_bx3_k(
    const float* __restrict__ A, int lda,
    const float* __restrict__ Bm, int ldb,
    float* __restrict__ C, int ldc,
    const float* __restrict__ bias,
    int M, int N, int K, int relu, int remapA)
{
  __shared__ short Ah[128 * LSTR];
  __shared__ short Al[128 * LSTR];
  __shared__ short Bh[128 * LSTR];
  __shared__ short Bl[128 * LSTR];

  const int tid = threadIdx.x;
  const int bm = blockIdx.x * 128;   // M-tiles on x: concurrent blocks share B panels
  const int bn = blockIdx.y * 128;

  // staging assignment: 256 threads, each loads 4 float4 per tile side
  const int kq = tid & 7;            // which float4 within the 32-wide K chunk
  const int r0 = tid >> 3;           // 0..31 base row

  const float* aP[4]; bool aV[4];
  const float* bP[4]; bool bV[4];
  #pragma unroll
  for (int p = 0; p < 4; ++p) {
    int gr = bm + r0 + p * 32;
    aV[p] = gr < M;
    int ar = gr;
    if (remapA) { int bq = gr / 255; ar = bq * 256 + (gr - bq * 255); }
    aP[p] = A + (long long)ar * lda + kq * 4;
    int gc = bn + r0 + p * 32;
    bV[p] = gc < N;
    bP[p] = Bm + (long long)gc * ldb + kq * 4;
  }

  const int lane = tid & 63;
  const int wm = ((tid >> 7) & 1) * 64;   // wave row quadrant
  const int wn = ((tid >> 6) & 1) * 64;   // wave col quadrant
  const int lr = lane & 15;               // fragment row/col within 16
  const int g8 = (lane >> 4) * 8;         // k-slot (8 bf16) for this lane group

  f32x4 acc[4][4];
  #pragma unroll
  for (int i = 0; i < 4; ++i)
    #pragma unroll
    for (int j = 0; j < 4; ++j)
      acc[i][j] = (f32x4){0.f, 0.f, 0.f, 0.f};

  for (int k0 = 0; k0 < K; k0 += 32) {
    // issue global loads early; latency hides under the barrier wait
    float4 av[4], bv[4];
    #pragma unroll
    for (int p = 0; p < 4; ++p) {
      av[p] = aV[p] ? *(const float4*)(aP[p] + k0) : make_float4(0.f, 0.f, 0.f, 0.f);
      bv[p] = bV[p] ? *(const float4*)(bP[p] + k0) : make_float4(0.f, 0.f, 0.f, 0.f);
    }
    __syncthreads();   // previous tile fully consumed
    #pragma unroll
    for (int p = 0; p < 4; ++p) {
      const int row = r0 + p * 32;
      const int off = row * LSTR + kq * 4;
      {
        unsigned ux = __float_as_uint(av[p].x), uy = __float_as_uint(av[p].y);
        unsigned uz = __float_as_uint(av[p].z), uw = __float_as_uint(av[p].w);
        unsigned h01 = (ux >> 16) | (uy & 0xffff0000u);
        unsigned h23 = (uz >> 16) | (uw & 0xffff0000u);
        float rx = av[p].x - __uint_as_float(ux & 0xffff0000u);
        float ry = av[p].y - __uint_as_float(uy & 0xffff0000u);
        float rz = av[p].z - __uint_as_float(uz & 0xffff0000u);
        float rw = av[p].w - __uint_as_float(uw & 0xffff0000u);
        unsigned l01 = (__float_as_uint(rx) >> 16) | (__float_as_uint(ry) & 0xffff0000u);
        unsigned l23 = (__float_as_uint(rz) >> 16) | (__float_as_uint(rw) & 0xffff0000u);
        *(uint2*)&Ah[off] = make_uint2(h01, h23);
        *(uint2*)&Al[off] = make_uint2(l01, l23);
      }
      {
        unsigned ux = __float_as_uint(bv[p].x), uy = __float_as_uint(bv[p].y);
        unsigned uz = __float_as_uint(bv[p].z), uw = __float_as_uint(bv[p].w);
        unsigned h01 = (ux >> 16) | (uy & 0xffff0000u);
        unsigned h23 = (uz >> 16) | (uw & 0xffff0000u);
        float rx = bv[p].x - __uint_as_float(ux & 0xffff0000u);
        float ry = bv[p].y - __uint_as_float(uy & 0xffff0000u);
        float rz = bv[p].z - __uint_as_float(uz & 0xffff0000u);
        float rw = bv[p].w - __uint_as_float(uw & 0xffff0000u);
        unsigned l01 = (__float_as_uint(rx) >> 16) | (__float_as_uint(ry) & 0xffff0000u);
        unsigned l23 = (__float_as_uint(rz) >> 16) | (__float_as_uint(rw) & 0xffff0000u);
        *(uint2*)&Bh[off] = make_uint2(h01, h23);
        *(uint2*)&Bl[off] = make_uint2(l01, l23);
      }
    }
    __syncthreads();

    short8 a_h[4], a_l[4], b_h[4], b_l[4];
    #pragma unroll
    for (int f = 0; f < 4; ++f) {
      const int ra = (wm + f * 16 + lr) * LSTR + g8;
      a_h[f] = *(const short8*)&Ah[ra];
      a_l[f] = *(const short8*)&Al[ra];
      const int rb = (wn + f * 16 + lr) * LSTR + g8;
      b_h[f] = *(const short8*)&Bh[rb];
      b_l[f] = *(const short8*)&Bl[rb];
    }
    #pragma unroll
    for (int i = 0; i < 4; ++i)
      #pragma unroll
      for (int j = 0; j < 4; ++j) {
        acc[i][j] = __builtin_amdgcn_mfma_f32_16x16x32_bf16(a_h[i], b_h[j], acc[i][j], 0, 0, 0);
        acc[i][j] = __builtin_amdgcn_mfma_f32_16x16x32_bf16(a_h[i], b_l[j], acc[i][j], 0, 0, 0);
        acc[i][j] = __builtin_amdgcn_mfma_f32_16x16x32_bf16(a_l[i], b_h[j], acc[i][j], 0, 0, 0);
      }
  }

  // epilogue: D mapping col = lane&15, row = (lane>>4)*4 + reg
  #pragma unroll
  for (int i = 0; i < 4; ++i) {
    #pragma unroll
    for (int ii = 0; ii < 4; ++ii) {
      int gr = bm + wm + i * 16 + (lane >> 4) * 4 + ii;
      if (gr >= M) continue;
      float* crow = C + (long long)gr * ldc;
      #pragma unroll
      for (int j = 0; j < 4; ++j) {
        int gc = bn + wn + j * 16 + lr;
        if (gc >= N) continue;
        float v = acc[i][j][ii];
        if (bias) v += bias[gc];
        if (relu) v = fmaxf(v, 0.f);
        crow[gc] = v;
      }
    }
  }
}

// ---------------- x = target_embed + sinusoid PE ----------------
__global__ void add_pe_k(const float* __restrict__ te, float* __restrict__ x)
{
  long long i = (long long)blockIdx.x * 256 + threadIdx.x;   // BB*SS*DD total
  int d = (int)(i % DD);
  int s = (int)((i / DD) % SS);
  int i2 = d >> 1;
  const float coef = -logf(10000.f) / (float)DD;
  float ang = (float)s * expf((float)(2 * i2) * coef);
  float pe = (d & 1) ? cosf(ang) : sinf(ang);
  x[i] = te[i] + pe;
}

// ---------------- row softmax over attention scores (opt causal) ----------------
__global__ __launch_bounds__(256) void softmax_rows_k(float* __restrict__ sc, int Lk, int causal)
{
  long long r = blockIdx.x;
  int q = (int)(r & (SS - 1));
  float* row = sc + r * (long long)Lk;
  int t = threadIdx.x;
  bool valid = (t < Lk) && (!causal || t <= q);
  float v = valid ? row[t] : -INFINITY;
  __shared__ float red[64];
  float m = blockMax(v, red);
  float e = valid ? expf(v - m) : 0.f;
  float s = blockSum(e, red);
  if (t < Lk) row[t] = e / s;
}

// ---------------- x = LayerNorm(x + t) * w + b (row = 768) ----------------
__global__ __launch_bounds__(256) void add_ln_k(
    float* __restrict__ x, const float* __restrict__ t,
    const float* __restrict__ w, const float* __restrict__ b)
{
  long long r = blockIdx.x;
  float* xr = x + r * DD;
  const float* tr = t + r * DD;
  int tid = threadIdx.x;
  float u[3]; float s = 0.f, sq = 0.f;
  #pragma unroll
  for (int i = 0; i < 3; ++i) {
    int c = tid + (i << 8);
    u[i] = xr[c] + tr[c];
    s += u[i]; sq += u[i] * u[i];
  }
  __shared__ float red[64];
  s  = blockSum(s, red);
  sq = blockSum(sq, red);
  float mean = s * (1.f / 768.f);
  float var  = sq * (1.f / 768.f) - mean * mean;
  float rs = rsqrtf(var + 1e-5f);
  #pragma unroll
  for (int i = 0; i < 3; ++i) {
    int c = tid + (i << 8);
    xr[c] = (u[i] - mean) * rs * w[c] + b[c];
  }
}

// ---------------- F_t = softmax(dec, axis=-1) ----------------
__global__ __launch_bounds__(256) void softmax_d_k(const float* __restrict__ x, float* __restrict__ out)
{
  int r = blockIdx.x;           // 0 .. BB*(SS-1)-1
  int b = r / 255, sI = r - b * 255;
  const float* xr = x + ((long long)(b * 256 + sI)) * DD;
  float* orow = out + (long long)r * DD;
  int t = threadIdx.x;
  float u[3]; float mx = -INFINITY;
  #pragma unroll
  for (int i = 0; i < 3; ++i) { u[i] = xr[t + (i << 8)]; mx = fmaxf(mx, u[i]); }
  __shared__ float red[64];
  float m = blockMax(mx, red);
  float e[3]; float s = 0.f;
  #pragma unroll
  for (int i = 0; i < 3; ++i) { e[i] = expf(u[i] - m); s += e[i]; }
  s = blockSum(s, red);
  float inv = 1.f / s;
  #pragma unroll
  for (int i = 0; i < 3; ++i) orow[t + (i << 8)] = e[i] * inv;
}

// ---------------- host-side launch helpers ----------------
static inline void gemm(hipStream_t st,
    const float* A, int lda, long long bsAb, long long bsAh,
    const float* Bm, int ldb, long long bsBb, long long bsBh, int transB,
    float* C, int ldc, long long bsCb, long long bsCh,
    const float* bias, int M, int N, int K, float alpha, int relu, int remapA,
    int nInner, int nBatch)
{
  dim3 g((N + 63) / 64, (M + 63) / 64, nBatch);
  gemm_k<<<g, 256, 0, st>>>(A, lda, bsAb, bsAh, Bm, ldb, bsBb, bsBh, transB,
                            C, ldc, bsCb, bsCh, bias, M, N, K, alpha, relu, remapA, nInner);
}

static inline void gemm3(hipStream_t st,
    const float* A, int lda, const float* Bm, int ldb,
    float* C, int ldc, const float* bias,
    int M, int N, int K, int relu, int remapA)
{
  dim3 g((M + 127) / 128, (N + 127) / 128, 1);
  gemm_bx3_k<<<g, 256, 0, st>>>(A, lda, Bm, ldb, C, ldc, bias, M, N, K, relu, remapA);
}

extern "C" void kernel_launch(void* const* d_in, const int* in_sizes, int n_in,
                              void* d_out, int out_size, void* d_ws, size_t ws_size,
                              hipStream_t stream)
{
  const float* fv          = (const float*)d_in[0];
  const float* te          = (const float*)d_in[1];
  const float* self_in_w   = (const float*)d_in[2];
  const float* self_in_b   = (const float*)d_in[3];
  const float* self_out_w  = (const float*)d_in[4];
  const float* self_out_b  = (const float*)d_in[5];
  const float* cross_in_w  = (const float*)d_in[6];
  const float* cross_in_b  = (const float*)d_in[7];
  const float* cross_out_w = (const float*)d_in[8];
  const float* cross_out_b = (const float*)d_in[9];
  const float* lin1_w      = (const float*)d_in[10];
  const float* lin1_b      = (const float*)d_in[11];
  const float* lin2_w      = (const float*)d_in[12];
  const float* lin2_b      = (const float*)d_in[13];
  const float* ln_w        = (const float*)d_in[14];
  const float* ln_b        = (const float*)d_in[15];
  const float* fc_out_w    = (const float*)d_in[16];
  float* out = (float*)d_out;

  // workspace layout (floats): x | buf1 (qkv / q+kv / ffn-h) | scores | obuf | tbuf
  float* x    = (float*)d_ws;                       // 4096*768
  float* buf1 = x    + (size_t)4096 * 768;          // 4096*2304
  float* sc   = buf1 + (size_t)4096 * 2304;         // 128*256*256
  float* obuf = sc   + (size_t)128 * 256 * 256;     // 4096*768
  float* tbuf = obuf + (size_t)4096 * 768;          // 4096*768

  const int M = BB * SS;                  // 4096
  const float ishd = 0.10206207261596577f; // 1/sqrt(96)

  add_pe_k<<<dim3((BB * SS * DD) / 256), 256, 0, stream>>>(te, x);

  for (int l = 0; l < NL; ++l) {
    // ======== self attention ========
    gemm3(stream, x, DD,
          self_in_w + (size_t)l * 3 * DD * DD, DD,
          buf1, 3 * DD,
          self_in_b + (size_t)l * 3 * DD, M, 3 * DD, DD, 0, 0);
    // scores = (q @ k^T) / sqrt(hd) per (b,h)
    gemm(stream, buf1, 3 * DD, (long long)SS * 3 * DD, HDD,
         buf1 + DD, 3 * DD, (long long)SS * 3 * DD, HDD, 0,
         sc, SS, (long long)NHH * SS * SS, (long long)SS * SS,
         nullptr, SS, SS, HDD, ishd, 0, 0, NHH, BB * NHH);
    softmax_rows_k<<<dim3(BB * NHH * SS), 256, 0, stream>>>(sc, SS, 1);
    // o = attn @ v
    gemm(stream, sc, SS, (long long)NHH * SS * SS, (long long)SS * SS,
         buf1 + 2 * DD, 3 * DD, (long long)SS * 3 * DD, HDD, 1,
         obuf, DD, (long long)SS * DD, HDD,
         nullptr, SS, HDD, SS, 1.f, 0, 0, NHH, BB * NHH);
    gemm3(stream, obuf, DD,
          self_out_w + (size_t)l * DD * DD, DD,
          tbuf, DD,
          self_out_b + (size_t)l * DD, M, DD, DD, 0, 0);
    add_ln_k<<<dim3(M), 256, 0, stream>>>(x, tbuf,
         ln_w + (size_t)(l * 3 + 0) * DD, ln_b + (size_t)(l * 3 + 0) * DD);

    // ======== cross attention ========
    float* qb  = buf1;                      // 4096*768
    float* kvb = buf1 + (size_t)M * DD;     // 3136*1536
    gemm3(stream, x, DD,
          cross_in_w + (size_t)l * 3 * DD * DD, DD,
          qb, DD,
          cross_in_b + (size_t)l * 3 * DD, M, DD, DD, 0, 0);
    gemm3(stream, fv, DD,
          cross_in_w + (size_t)l * 3 * DD * DD + (size_t)DD * DD, DD,
          kvb, 2 * DD,
          cross_in_b + (size_t)l * 3 * DD + DD, BB * NV, 2 * DD, DD, 0, 0);
    gemm(stream, qb, DD, (long long)SS * DD, HDD,
         kvb, 2 * DD, (long long)NV * 2 * DD, HDD, 0,
         sc, NV, (long long)NHH * SS * NV, (long long)SS * NV,
         nullptr, SS, NV, HDD, ishd, 0, 0, NHH, BB * NHH);
    softmax_rows_k<<<dim3(BB * NHH * SS), 256, 0, stream>>>(sc, NV, 0);
    gemm(stream, sc, NV, (long long)NHH * SS * NV, (long long)SS * NV,
         kvb + DD, 2 * DD, (long long)NV * 2 * DD, HDD, 1,
         obuf, DD, (long long)SS * DD, HDD,
         nullptr, SS, HDD, NV, 1.f, 0, 0, NHH, BB * NHH);
    gemm3(stream, obuf, DD,
          cross_out_w + (size_t)l * DD * DD, DD,
          tbuf, DD,
          cross_out_b + (size_t)l * DD, M, DD, DD, 0, 0);
    add_ln_k<<<dim3(M), 256, 0, stream>>>(x, tbuf,
         ln_w + (size_t)(l * 3 + 1) * DD, ln_b + (size_t)(l * 3 + 1) * DD);

    // ======== FFN ========
    gemm3(stream, x, DD,
          lin1_w + (size_t)l * FFD * DD, DD,
          buf1, FFD,
          lin1_b + (size_t)l * FFD, M, FFD, DD, 1, 0);
    gemm3(stream, buf1, FFD,
          lin2_w + (size_t)l * DD * FFD, FFD,
          tbuf, DD,
          lin2_b + (size_t)l * DD, M, DD, FFD, 0, 0);
    add_ln_k<<<dim3(M), 256, 0, stream>>>(x, tbuf,
         ln_w + (size_t)(l * 3 + 2) * DD, ln_b + (size_t)(l * 3 + 2) * DD);
  }

  // logits = dec @ fc_out_w^T   (dec rows remapped from x)
  gemm3(stream, x, DD,
        fc_out_w, DD,
        out, VV,
        nullptr, BB * (SS - 1), VV, DD, 0, 1);
  // F_t = softmax(dec, axis=-1)
  softmax_d_k<<<dim3(BB * (SS - 1)), 256, 0, stream>>>(x, out + (size_t)BB * (SS - 1) * VV);
}

// Round 2
// 5756.166 us; speedup vs baseline: 2.4473x; 1.4630x over previous
//
#include <hip/hip_runtime.h>
#include <math.h>

// Problem constants
#define BB   16
#define SS   256
#define NV   196
#define DD   768
#define FFD  2048
#define VV   30522
#define NL   6
#define NHH  8
#define HDD  96

typedef __attribute__((ext_vector_type(8))) short short8;
typedef __attribute__((ext_vector_type(4))) float f32x4;

// ---------------- helpers ----------------
__device__ __forceinline__ void split2(float v, short& h, short& l) {
  unsigned u = __float_as_uint(v);
  h = (short)(u >> 16);
  float r = v - __uint_as_float(u & 0xffff0000u);
  l = (short)(__float_as_uint(r) >> 16);
}
// fragment-tiled element index: tiles of 16 rows x 32 cols, 512 el each.
// lane = ((c%32)/8)*16 + r%16 holds 8 consecutive c.
__device__ __forceinline__ size_t tiled_el(int r, int c, int KT) {
  return ((size_t)(r >> 4) * KT + (c >> 5)) * 512
       + ((((c >> 3) & 3) << 4) + (r & 15)) * 8 + (c & 7);
}

// ---------------- block reductions (blockDim.x == 256 -> 4 waves) ----------------
__device__ __forceinline__ float blockSum(float v, float* red) {
  int lane = threadIdx.x & 63, w = threadIdx.x >> 6;
  #pragma unroll
  for (int o = 32; o; o >>= 1) v += __shfl_down(v, o);
  __syncthreads();
  if (lane == 0) red[w] = v;
  __syncthreads();
  return red[0] + red[1] + red[2] + red[3];
}

__device__ __forceinline__ float blockMax(float v, float* red) {
  int lane = threadIdx.x & 63, w = threadIdx.x >> 6;
  #pragma unroll
  for (int o = 32; o; o >>= 1) v = fmaxf(v, __shfl_down(v, o));
  __syncthreads();
  if (lane == 0) red[w] = v;
  __syncthreads();
  return fmaxf(fmaxf(red[0], red[1]), fmaxf(red[2], red[3]));
}

// ---------------- generic batched GEMM (fp32 VALU path, small attention GEMMs) ----
// Optional split-tiled output (sh/sl): absolute row = zb*sRowZb + gr, col = zh*sColZh + gc.
__global__ __launch_bounds__(256) void gemm_k(
    const float* __restrict__ A, int lda, long long bsAb, long long bsAh,
    const float* __restrict__ Bm, int ldb, long long bsBb, long long bsBh, int transB,
    float* __restrict__ C, int ldc, long long bsCb, long long bsCh,
    const float* __restrict__ bias,
    int M, int N, int K, float alpha, int relu, int remapA, int nInner,
    short* __restrict__ sh, short* __restrict__ sl, int sK, int sRowZb, int sColZh)
{
  int z = blockIdx.z;
  int zb = z / nInner, zh = z - zb * nInner;
  A  += zb * bsAb + zh * bsAh;
  Bm += zb * bsBb + zh * bsBh;
  C  += zb * bsCb + zh * bsCh;

  const int bm = blockIdx.y << 6, bn = blockIdx.x << 6;
  const int tid = threadIdx.x;
  const int tx = tid & 15, ty = tid >> 4;

  __shared__ __align__(16) float As[16][68];
  __shared__ __align__(16) float Bs[16][68];

  const float* aptr[4]; bool aval[4];
  {
    int lm0 = tid >> 4;
    #pragma unroll
    for (int p = 0; p < 4; ++p) {
      int gr = bm + lm0 + p * 16;
      aval[p] = gr < M;
      int ar = gr;
      if (remapA) { int bq = gr / 255; ar = bq * 256 + (gr - bq * 255); }
      aptr[p] = A + (long long)ar * lda;
    }
  }
  const float* bptr[4]; bool bval[4];
  if (!transB) {
    int ln0 = tid >> 4;
    #pragma unroll
    for (int p = 0; p < 4; ++p) {
      int gn = bn + ln0 + p * 16;
      bval[p] = gn < N;
      bptr[p] = Bm + (long long)gn * ldb;
    }
  }

  float acc[4][4] = {{0.f}};

  for (int k0 = 0; k0 < K; k0 += 16) {
    int lk = tid & 15;
    int gk = k0 + lk;
    bool kok = gk < K;
    {
      int lm0 = tid >> 4;
      #pragma unroll
      for (int p = 0; p < 4; ++p) {
        float v = 0.f;
        if (aval[p] && kok) v = aptr[p][gk];
        As[lk][lm0 + p * 16] = v;
      }
    }
    if (!transB) {
      int ln0 = tid >> 4;
      #pragma unroll
      for (int p = 0; p < 4; ++p) {
        float v = 0.f;
        if (bval[p] && kok) v = bptr[p][gk];
        Bs[lk][ln0 + p * 16] = v;
      }
    } else {
      int ln = tid & 63;
      int lk0 = tid >> 6;
      int gn = bn + ln;
      #pragma unroll
      for (int p = 0; p < 4; ++p) {
        int kk = lk0 + p * 4;
        int gkk = k0 + kk;
        float v = 0.f;
        if (gn < N && gkk < K) v = Bm[(long long)gkk * ldb + gn];
        Bs[kk][ln] = v;
      }
    }
    __syncthreads();
    #pragma unroll
    for (int kk = 0; kk < 16; ++kk) {
      float4 av = *(const float4*)&As[kk][ty << 2];
      float4 bv = *(const float4*)&Bs[kk][tx << 2];
      float a_[4] = {av.x, av.y, av.z, av.w};
      float b_[4] = {bv.x, bv.y, bv.z, bv.w};
      #pragma unroll
      for (int i = 0; i < 4; ++i)
        #pragma unroll
        for (int j = 0; j < 4; ++j)
          acc[i][j] += a_[i] * b_[j];
    }
    __syncthreads();
  }

  #pragma unroll
  for (int i = 0; i < 4; ++i) {
    int gr = bm + (ty << 2) + i;
    if (gr >= M) continue;
    float* crow = C + (long long)gr * ldc;
    #pragma unroll
    for (int j = 0; j < 4; ++j) {
      int gc = bn + (tx << 2) + j;
      if (gc >= N) continue;
      float v = acc[i][j] * alpha;
      if (bias) v += bias[gc];
      if (relu) v = fmaxf(v, 0.f);
      crow[gc] = v;
      if (sh) {
        int Rabs = zb * sRowZb + gr;
        int Cabs = zh * sColZh + gc;
        size_t el = tiled_el(Rabs, Cabs, sK >> 5);
        short hh, ll; split2(v, hh, ll);
        sh[el] = hh; sl[el] = ll;
      }
    }
  }
}

// ---------------- FALLBACK: round-1 split-bf16 MFMA GEMM (in-kernel conversion) ----
#define LSTR 40
__global__ __launch_bounds__(256, 2) void gemm_bx3_k(
    const float* __restrict__ A, int lda,
    const float* __restrict__ Bm, int ldb,
    float* __restrict__ C, int ldc,
    const float* __restrict__ bias,
    int M, int N, int K, int relu, int remapA)
{
  __shared__ short Ah[128 * LSTR];
  __shared__ short Al[128 * LSTR];
  __shared__ short Bh[128 * LSTR];
  __shared__ short Bl[128 * LSTR];

  const int tid = threadIdx.x;
  const int bm = blockIdx.x * 128;
  const int bn = blockIdx.y * 128;

  const int kq = tid & 7;
  const int r0 = tid >> 3;

  const float* aP[4]; bool aV[4];
  const float* bP[4]; bool bV[4];
  #pragma unroll
  for (int p = 0; p < 4; ++p) {
    int gr = bm + r0 + p * 32;
    aV[p] = gr < M;
    int ar = gr;
    if (remapA) { int bq = gr / 255; ar = bq * 256 + (gr - bq * 255); }
    aP[p] = A + (long long)ar * lda + kq * 4;
    int gc = bn + r0 + p * 32;
    bV[p] = gc < N;
    bP[p] = Bm + (long long)gc * ldb + kq * 4;
  }

  const int lane = tid & 63;
  const int wm = ((tid >> 7) & 1) * 64;
  const int wn = ((tid >> 6) & 1) * 64;
  const int lr = lane & 15;
  const int g8 = (lane >> 4) * 8;

  f32x4 acc[4][4];
  #pragma unroll
  for (int i = 0; i < 4; ++i)
    #pragma unroll
    for (int j = 0; j < 4; ++j)
      acc[i][j] = (f32x4){0.f, 0.f, 0.f, 0.f};

  for (int k0 = 0; k0 < K; k0 += 32) {
    float4 av[4], bv[4];
    #pragma unroll
    for (int p = 0; p < 4; ++p) {
      av[p] = aV[p] ? *(const float4*)(aP[p] + k0) : make_float4(0.f, 0.f, 0.f, 0.f);
      bv[p] = bV[p] ? *(const float4*)(bP[p] + k0) : make_float4(0.f, 0.f, 0.f, 0.f);
    }
    __syncthreads();
    #pragma unroll
    for (int p = 0; p < 4; ++p) {
      const int row = r0 + p * 32;
      const int off = row * LSTR + kq * 4;
      {
        unsigned ux = __float_as_uint(av[p].x), uy = __float_as_uint(av[p].y);
        unsigned uz = __float_as_uint(av[p].z), uw = __float_as_uint(av[p].w);
        unsigned h01 = (ux >> 16) | (uy & 0xffff0000u);
        unsigned h23 = (uz >> 16) | (uw & 0xffff0000u);
        float rx = av[p].x - __uint_as_float(ux & 0xffff0000u);
        float ry = av[p].y - __uint_as_float(uy & 0xffff0000u);
        float rz = av[p].z - __uint_as_float(uz & 0xffff0000u);
        float rw = av[p].w - __uint_as_float(uw & 0xffff0000u);
        unsigned l01 = (__float_as_uint(rx) >> 16) | (__float_as_uint(ry) & 0xffff0000u);
        unsigned l23 = (__float_as_uint(rz) >> 16) | (__float_as_uint(rw) & 0xffff0000u);
        *(uint2*)&Ah[off] = make_uint2(h01, h23);
        *(uint2*)&Al[off] = make_uint2(l01, l23);
      }
      {
        unsigned ux = __float_as_uint(bv[p].x), uy = __float_as_uint(bv[p].y);
        unsigned uz = __float_as_uint(bv[p].z), uw = __float_as_uint(bv[p].w);
        unsigned h01 = (ux >> 16) | (uy & 0xffff0000u);
        unsigned h23 = (uz >> 16) | (uw & 0xffff0000u);
        float rx = bv[p].x - __uint_as_float(ux & 0xffff0000u);
        float ry = bv[p].y - __uint_as_float(uy & 0xffff0000u);
        float rz = bv[p].z - __uint_as_float(uz & 0xffff0000u);
        float rw = bv[p].w - __uint_as_float(uw & 0xffff0000u);
        unsigned l01 = (__float_as_uint(rx) >> 16) | (__float_as_uint(ry) & 0xffff0000u);
        unsigned l23 = (__float_as_uint(rz) >> 16) | (__float_as_uint(rw) & 0xffff0000u);
        *(uint2*)&Bh[off] = make_uint2(h01, h23);
        *(uint2*)&Bl[off] = make_uint2(l01, l23);
      }
    }
    __syncthreads();

    short8 a_h[4], a_l[4], b_h[4], b_l[4];
    #pragma unroll
    for (int f = 0; f < 4; ++f) {
      const int ra = (wm + f * 16 + lr) * LSTR + g8;
      a_h[f] = *(const short8*)&Ah[ra];
      a_l[f] = *(const short8*)&Al[ra];
      const int rb = (wn + f * 16 + lr) * LSTR + g8;
      b_h[f] = *(const short8*)&Bh[rb];
      b_l[f] = *(const short8*)&Bl[rb];
    }
    #pragma unroll
    for (int i = 0; i < 4; ++i)
      #pragma unroll
      for (int j = 0; j < 4; ++j) {
        acc[i][j] = __builtin_amdgcn_mfma_f32_16x16x32_bf16(a_h[i], b_h[j], acc[i][j], 0, 0, 0);
        acc[i][j] = __builtin_amdgcn_mfma_f32_16x16x32_bf16(a_h[i], b_l[j], acc[i][j], 0, 0, 0);
        acc[i][j] = __builtin_amdgcn_mfma_f32_16x16x32_bf16(a_l[i], b_h[j], acc[i][j], 0, 0, 0);
      }
  }

  #pragma unroll
  for (int i = 0; i < 4; ++i) {
    #pragma unroll
    for (int ii = 0; ii < 4; ++ii) {
      int gr = bm + wm + i * 16 + (lane >> 4) * 4 + ii;
      if (gr >= M) continue;
      float* crow = C + (long long)gr * ldc;
      #pragma unroll
      for (int j = 0; j < 4; ++j) {
        int gc = bn + wn + j * 16 + lr;
        if (gc >= N) continue;
        float v = acc[i][j][ii];
        if (bias) v += bias[gc];
        if (relu) v = fmaxf(v, 0.f);
        crow[gc] = v;
      }
    }
  }
}

// ---------------- fp32 -> fragment-tiled (hi,lo) bf16 planes ----------------
// src: R x K row-major (ld=K). dst tiles cover Rp x K (pad rows zero). 1 wave = 1 tile.
__global__ __launch_bounds__(256) void split_tile_k(
    const float* __restrict__ src, int R, int K,
    short* __restrict__ dh, short* __restrict__ dl, int tiles)
{
  int tile = blockIdx.x * 4 + (threadIdx.x >> 6);
  if (tile >= tiles) return;
  int lane = threadIdx.x & 63;
  int KT = K >> 5;
  int rt = tile / KT, kt = tile - rt * KT;
  int row = rt * 16 + (lane & 15);
  int col = kt * 32 + ((lane >> 4) << 3);
  float f[8] = {0.f,0.f,0.f,0.f,0.f,0.f,0.f,0.f};
  if (row < R) {
    const float* p = src + (size_t)row * K + col;
    float4 v0 = *(const float4*)p;
    float4 v1 = *(const float4*)(p + 4);
    f[0]=v0.x; f[1]=v0.y; f[2]=v0.z; f[3]=v0.w;
    f[4]=v1.x; f[5]=v1.y; f[6]=v1.z; f[7]=v1.w;
  }
  short8 hv, lv;
  #pragma unroll
  for (int j = 0; j < 8; ++j) {
    short hh, ll; split2(f[j], hh, ll);
    hv[j] = hh; lv[j] = ll;
  }
  size_t o = (size_t)tile * 512 + lane * 8;
  *(short8*)(dh + o) = hv;
  *(short8*)(dl + o) = lv;
}

// ---------------- fragment-direct split-bf16 MFMA GEMM ----------------
// A,B pre-split fragment-tiled (hi/lo planes). C = A @ B^T + bias (+relu).
// No LDS, no barriers. 128x128 tile, 2x2 waves, 64x64/wave, 16x16x32 MFMA x3 terms.
// remapC: physical row gr -> skip if gr%256==255 else out row (gr/256)*255 + gr%256.
// Optional split-tiled output (sh/sl planes, inner dim sK).
__global__ __launch_bounds__(256, 2) void gemm_bf3_k(
    const short* __restrict__ Ah, const short* __restrict__ Al,
    const short* __restrict__ Bh, const short* __restrict__ Bl,
    float* __restrict__ C, int ldc, const float* __restrict__ bias,
    int M, int N, int K, int relu, int remapC,
    short* __restrict__ sh, short* __restrict__ sl, int sK)
{
  const int tid = threadIdx.x, lane = tid & 63;
  const int KT = K >> 5;
  const int bm = blockIdx.x << 7, bn = blockIdx.y << 7;
  const int wm = ((tid >> 7) & 1) << 6, wn = ((tid >> 6) & 1) << 6;
  const long long fs = (long long)KT * 512;   // row-tile stride in elements

  const short* pah = Ah + (long long)((bm + wm) >> 4) * fs + lane * 8;
  const short* pal = Al + (long long)((bm + wm) >> 4) * fs + lane * 8;
  const short* pbh = Bh + (long long)((bn + wn) >> 4) * fs + lane * 8;
  const short* pbl = Bl + (long long)((bn + wn) >> 4) * fs + lane * 8;

  f32x4 acc[4][4];
  #pragma unroll
  for (int i = 0; i < 4; ++i)
    #pragma unroll
    for (int j = 0; j < 4; ++j)
      acc[i][j] = (f32x4){0.f, 0.f, 0.f, 0.f};

  #pragma unroll 2
  for (int kt = 0; kt < KT; ++kt) {
    short8 ah[4], al[4], bh[4], bl[4];
    #pragma unroll
    for (int f = 0; f < 4; ++f) {
      ah[f] = *(const short8*)(pah + f * fs);
      al[f] = *(const short8*)(pal + f * fs);
      bh[f] = *(const short8*)(pbh + f * fs);
      bl[f] = *(const short8*)(pbl + f * fs);
    }
    pah += 512; pal += 512; pbh += 512; pbl += 512;
    #pragma unroll
    for (int i = 0; i < 4; ++i)
      #pragma unroll
      for (int j = 0; j < 4; ++j) {
        acc[i][j] = __builtin_amdgcn_mfma_f32_16x16x32_bf16(ah[i], bh[j], acc[i][j], 0, 0, 0);
        acc[i][j] = __builtin_amdgcn_mfma_f32_16x16x32_bf16(ah[i], bl[j], acc[i][j], 0, 0, 0);
        acc[i][j] = __builtin_amdgcn_mfma_f32_16x16x32_bf16(al[i], bh[j], acc[i][j], 0, 0, 0);
      }
  }

  const int lr = lane & 15, lg = lane >> 4;
  #pragma unroll
  for (int i = 0; i < 4; ++i) {
    #pragma unroll
    for (int ii = 0; ii < 4; ++ii) {
      int gr = bm + wm + i * 16 + lg * 4 + ii;
      if (gr >= M) continue;
      int orow = gr;
      if (remapC) {
        int s = gr & 255;
        if (s == 255) continue;
        orow = (gr >> 8) * 255 + s;
      }
      float* crow = C + (long long)orow * ldc;
      #pragma unroll
      for (int j = 0; j < 4; ++j) {
        int gc = bn + wn + j * 16 + lr;
        if (gc >= N) continue;
        float v = acc[i][j][ii];
        if (bias) v += bias[gc];
        if (relu) v = fmaxf(v, 0.f);
        crow[gc] = v;
        if (sh) {
          size_t el = tiled_el(gr, gc, sK >> 5);
          short hh, ll; split2(v, hh, ll);
          sh[el] = hh; sl[el] = ll;
        }
      }
    }
  }
}

// ---------------- x = target_embed + sinusoid PE (opt split out, K=768) ----------
__global__ void add_pe_k(const float* __restrict__ te, float* __restrict__ x,
                         short* __restrict__ sh, short* __restrict__ sl)
{
  long long i = (long long)blockIdx.x * 256 + threadIdx.x;
  int d = (int)(i % DD);
  int r = (int)(i / DD);
  int s = r & (SS - 1);
  int i2 = d >> 1;
  const float coef = -logf(10000.f) / (float)DD;
  float ang = (float)s * expf((float)(2 * i2) * coef);
  float pe = (d & 1) ? cosf(ang) : sinf(ang);
  float v = te[i] + pe;
  x[i] = v;
  if (sh) {
    size_t el = tiled_el(r, d, DD >> 5);
    short hh, ll; split2(v, hh, ll);
    sh[el] = hh; sl[el] = ll;
  }
}

// ---------------- row softmax over attention scores (opt causal) ----------------
__global__ __launch_bounds__(256) void softmax_rows_k(float* __restrict__ sc, int Lk, int causal)
{
  long long r = blockIdx.x;
  int q = (int)(r & (SS - 1));
  float* row = sc + r * (long long)Lk;
  int t = threadIdx.x;
  bool valid = (t < Lk) && (!causal || t <= q);
  float v = valid ? row[t] : -INFINITY;
  __shared__ float red[64];
  float m = blockMax(v, red);
  float e = valid ? expf(v - m) : 0.f;
  float s = blockSum(e, red);
  if (t < Lk) row[t] = e / s;
}

// ---------------- x = LayerNorm(x + t) * w + b (row = 768, opt split out) -------
__global__ __launch_bounds__(256) void add_ln_k(
    float* __restrict__ x, const float* __restrict__ t,
    const float* __restrict__ w, const float* __restrict__ b,
    short* __restrict__ sh, short* __restrict__ sl)
{
  long long r = blockIdx.x;
  float* xr = x + r * DD;
  const float* tr = t + r * DD;
  int tid = threadIdx.x;
  float u[3]; float s = 0.f, sq = 0.f;
  #pragma unroll
  for (int i = 0; i < 3; ++i) {
    int c = tid + (i << 8);
    u[i] = xr[c] + tr[c];
    s += u[i]; sq += u[i] * u[i];
  }
  __shared__ float red[64];
  s  = blockSum(s, red);
  sq = blockSum(sq, red);
  float mean = s * (1.f / 768.f);
  float var  = sq * (1.f / 768.f) - mean * mean;
  float rs = rsqrtf(var + 1e-5f);
  #pragma unroll
  for (int i = 0; i < 3; ++i) {
    int c = tid + (i << 8);
    float v = (u[i] - mean) * rs * w[c] + b[c];
    xr[c] = v;
    if (sh) {
      size_t el = tiled_el((int)r, c, DD >> 5);
      short hh, ll; split2(v, hh, ll);
      sh[el] = hh; sl[el] = ll;
    }
  }
}

// ---------------- F_t = softmax(dec, axis=-1) ----------------
__global__ __launch_bounds__(256) void softmax_d_k(const float* __restrict__ x, float* __restrict__ out)
{
  int r = blockIdx.x;
  int b = r / 255, sI = r - b * 255;
  const float* xr = x + ((long long)(b * 256 + sI)) * DD;
  float* orow = out + (long long)r * DD;
  int t = threadIdx.x;
  float u[3]; float mx = -INFINITY;
  #pragma unroll
  for (int i = 0; i < 3; ++i) { u[i] = xr[t + (i << 8)]; mx = fmaxf(mx, u[i]); }
  __shared__ float red[64];
  float m = blockMax(mx, red);
  float e[3]; float s = 0.f;
  #pragma unroll
  for (int i = 0; i < 3; ++i) { e[i] = expf(u[i] - m); s += e[i]; }
  s = blockSum(s, red);
  float inv = 1.f / s;
  #pragma unroll
  for (int i = 0; i < 3; ++i) orow[t + (i << 8)] = e[i] * inv;
}

// ---------------- host-side launch helpers ----------------
static inline void gemm(hipStream_t st,
    const float* A, int lda, long long bsAb, long long bsAh,
    const float* Bm, int ldb, long long bsBb, long long bsBh, int transB,
    float* C, int ldc, long long bsCb, long long bsCh,
    const float* bias, int M, int N, int K, float alpha, int relu, int remapA,
    int nInner, int nBatch,
    short* sh = nullptr, short* sl = nullptr, int sK = 768, int sRowZb = 0, int sColZh = 0)
{
  dim3 g((N + 63) / 64, (M + 63) / 64, nBatch);
  gemm_k<<<g, 256, 0, st>>>(A, lda, bsAb, bsAh, Bm, ldb, bsBb, bsBh, transB,
                            C, ldc, bsCb, bsCh, bias, M, N, K, alpha, relu, remapA, nInner,
                            sh, sl, sK, sRowZb, sColZh);
}

static inline void gemm3(hipStream_t st,
    const float* A, int lda, const float* Bm, int ldb,
    float* C, int ldc, const float* bias,
    int M, int N, int K, int relu, int remapA)
{
  dim3 g((M + 127) / 128, (N + 127) / 128, 1);
  gemm_bx3_k<<<g, 256, 0, st>>>(A, lda, Bm, ldb, C, ldc, bias, M, N, K, relu, remapA);
}

static inline void gemmF(hipStream_t st,
    const short* Ah, const short* Al, const short* Bh, const short* Bl,
    float* C, int ldc, const float* bias,
    int M, int N, int K, int relu, int remapC,
    short* sh = nullptr, short* sl = nullptr, int sK = 768)
{
  dim3 g((M + 127) / 128, (N + 127) / 128, 1);
  gemm_bf3_k<<<g, 256, 0, st>>>(Ah, Al, Bh, Bl, C, ldc, bias, M, N, K, relu, remapC, sh, sl, sK);
}

static inline void conv(hipStream_t st, const float* src, int R, int Rp, int K,
                        short* dh, short* dl)
{
  int tiles = (Rp / 16) * (K / 32);
  split_tile_k<<<dim3((tiles + 3) / 4), 256, 0, st>>>(src, R, K, dh, dl, tiles);
}

extern "C" void kernel_launch(void* const* d_in, const int* in_sizes, int n_in,
                              void* d_out, int out_size, void* d_ws, size_t ws_size,
                              hipStream_t stream)
{
  const float* fv          = (const float*)d_in[0];
  const float* te          = (const float*)d_in[1];
  const float* self_in_w   = (const float*)d_in[2];
  const float* self_in_b   = (const float*)d_in[3];
  const float* self_out_w  = (const float*)d_in[4];
  const float* self_out_b  = (const float*)d_in[5];
  const float* cross_in_w  = (const float*)d_in[6];
  const float* cross_in_b  = (const float*)d_in[7];
  const float* cross_out_w = (const float*)d_in[8];
  const float* cross_out_b = (const float*)d_in[9];
  const float* lin1_w      = (const float*)d_in[10];
  const float* lin1_b      = (const float*)d_in[11];
  const float* lin2_w      = (const float*)d_in[12];
  const float* lin2_b      = (const float*)d_in[13];
  const float* ln_w        = (const float*)d_in[14];
  const float* ln_b        = (const float*)d_in[15];
  const float* fc_out_w    = (const float*)d_in[16];
  float* out = (float*)d_out;

  // fp32 region (floats)
  float* x    = (float*)d_ws;                       // 4096*768
  float* buf1 = x    + (size_t)4096 * 768;          // 4096*2304
  float* sc   = buf1 + (size_t)4096 * 2304;         // 128*256*256
  float* obuf = sc   + (size_t)128 * 256 * 256;     // 4096*768
  float* tbuf = obuf + (size_t)4096 * 768;          // 4096*768

  const int M = BB * SS;                  // 4096
  const float ishd = 0.10206207261596577f; // 1/sqrt(96)

  // split-plane region (shorts), after fp32 region
  const size_t eXS  = (size_t)4096 * 768;
  const size_t eFV  = (size_t)3200 * 768;
  const size_t eOB  = (size_t)4096 * 768;
  const size_t eFF  = (size_t)4096 * 2048;
  const size_t eWSI = (size_t)13824 * 768;
  const size_t eWSO = (size_t)4608 * 768;
  const size_t eWCI = (size_t)13824 * 768;
  const size_t eWCO = (size_t)4608 * 768;
  const size_t eWL1 = (size_t)12288 * 768;
  const size_t eWL2 = (size_t)4608 * 2048;
  const size_t eWFC = (size_t)30592 * 768;
  const size_t elSum = eXS+eFV+eOB+eFF+eWSI+eWSO+eWCI+eWCO+eWL1+eWL2+eWFC;
  const size_t NEED = (size_t)27262976 * 4 + elSum * 4;  // fp32 region + 2 short planes/el

  if (ws_size >= NEED) {
    // ================= fast path: fragment-direct MFMA =================
    short* sp = (short*)(tbuf + (size_t)4096 * 768);
    short *xsH = sp,        *xsL = xsH + eXS;   sp = xsL + eXS;
    short *fvH = sp,        *fvL = fvH + eFV;   sp = fvL + eFV;
    short *obH = sp,        *obL = obH + eOB;   sp = obL + eOB;
    short *ffH = sp,        *ffL = ffH + eFF;   sp = ffL + eFF;
    short *wsiH = sp,       *wsiL = wsiH + eWSI; sp = wsiL + eWSI;
    short *wsoH = sp,       *wsoL = wsoH + eWSO; sp = wsoL + eWSO;
    short *wciH = sp,       *wciL = wciH + eWCI; sp = wciL + eWCI;
    short *wcoH = sp,       *wcoL = wcoH + eWCO; sp = wcoL + eWCO;
    short *wl1H = sp,       *wl1L = wl1H + eWL1; sp = wl1L + eWL1;
    short *wl2H = sp,       *wl2L = wl2H + eWL2; sp = wl2L + eWL2;
    short *wfcH = sp,       *wfcL = wfcH + eWFC;

    // convert all weights + fv once per launch (memory-bound, ~100 us total)
    conv(stream, self_in_w,  13824, 13824, 768,  wsiH, wsiL);
    conv(stream, self_out_w,  4608,  4608, 768,  wsoH, wsoL);
    conv(stream, cross_in_w, 13824, 13824, 768,  wciH, wciL);
    conv(stream, cross_out_w, 4608,  4608, 768,  wcoH, wcoL);
    conv(stream, lin1_w,     12288, 12288, 768,  wl1H, wl1L);
    conv(stream, lin2_w,      4608,  4608, 2048, wl2H, wl2L);
    conv(stream, fc_out_w,   30522, 30592, 768,  wfcH, wfcL);
    conv(stream, fv,          3136,  3200, 768,  fvH,  fvL);

    add_pe_k<<<dim3((BB * SS * DD) / 256), 256, 0, stream>>>(te, x, xsH, xsL);

    const size_t lWI = (size_t)2304 * 768;   // per-layer el strides
    const size_t lWO = (size_t)768 * 768;
    const size_t lW1 = (size_t)2048 * 768;
    const size_t lW2 = (size_t)768 * 2048;

    for (int l = 0; l < NL; ++l) {
      // ======== self attention ========
      gemmF(stream, xsH, xsL, wsiH + l * lWI, wsiL + l * lWI,
            buf1, 3 * DD, self_in_b + (size_t)l * 3 * DD, M, 3 * DD, DD, 0, 0);
      gemm(stream, buf1, 3 * DD, (long long)SS * 3 * DD, HDD,
           buf1 + DD, 3 * DD, (long long)SS * 3 * DD, HDD, 0,
           sc, SS, (long long)NHH * SS * SS, (long long)SS * SS,
           nullptr, SS, SS, HDD, ishd, 0, 0, NHH, BB * NHH);
      softmax_rows_k<<<dim3(BB * NHH * SS), 256, 0, stream>>>(sc, SS, 1);
      gemm(stream, sc, SS, (long long)NHH * SS * SS, (long long)SS * SS,
           buf1 + 2 * DD, 3 * DD, (long long)SS * 3 * DD, HDD, 1,
           obuf, DD, (long long)SS * DD, HDD,
           nullptr, SS, HDD, SS, 1.f, 0, 0, NHH, BB * NHH,
           obH, obL, DD, SS, HDD);
      gemmF(stream, obH, obL, wsoH + l * lWO, wsoL + l * lWO,
            tbuf, DD, self_out_b + (size_t)l * DD, M, DD, DD, 0, 0);
      add_ln_k<<<dim3(M), 256, 0, stream>>>(x, tbuf,
           ln_w + (size_t)(l * 3 + 0) * DD, ln_b + (size_t)(l * 3 + 0) * DD, xsH, xsL);

      // ======== cross attention ========
      float* qb  = buf1;
      float* kvb = buf1 + (size_t)M * DD;
      gemmF(stream, xsH, xsL, wciH + l * lWI, wciL + l * lWI,
            qb, DD, cross_in_b + (size_t)l * 3 * DD, M, DD, DD, 0, 0);
      gemmF(stream, fvH, fvL, wciH + l * lWI + lWO, wciL + l * lWI + lWO,
            kvb, 2 * DD, cross_in_b + (size_t)l * 3 * DD + DD, BB * NV, 2 * DD, DD, 0, 0);
      gemm(stream, qb, DD, (long long)SS * DD, HDD,
           kvb, 2 * DD, (long long)NV * 2 * DD, HDD, 0,
           sc, NV, (long long)NHH * SS * NV, (long long)SS * NV,
           nullptr, SS, NV, HDD, ishd, 0, 0, NHH, BB * NHH);
      softmax_rows_k<<<dim3(BB * NHH * SS), 256, 0, stream>>>(sc, NV, 0);
      gemm(stream, sc, NV, (long long)NHH * SS * NV, (long long)SS * NV,
           kvb + DD, 2 * DD, (long long)NV * 2 * DD, HDD, 1,
           obuf, DD, (long long)SS * DD, HDD,
           nullptr, SS, HDD, NV, 1.f, 0, 0, NHH, BB * NHH,
           obH, obL, DD, SS, HDD);
      gemmF(stream, obH, obL, wcoH + l * lWO, wcoL + l * lWO,
            tbuf, DD, cross_out_b + (size_t)l * DD, M, DD, DD, 0, 0);
      add_ln_k<<<dim3(M), 256, 0, stream>>>(x, tbuf,
           ln_w + (size_t)(l * 3 + 1) * DD, ln_b + (size_t)(l * 3 + 1) * DD, xsH, xsL);

      // ======== FFN ========
      gemmF(stream, xsH, xsL, wl1H + l * lW1, wl1L + l * lW1,
            buf1, FFD, lin1_b + (size_t)l * FFD, M, FFD, DD, 1, 0,
            ffH, ffL, FFD);
      gemmF(stream, ffH, ffL, wl2H + l * lW2, wl2L + l * lW2,
            tbuf, DD, lin2_b + (size_t)l * DD, M, DD, FFD, 0, 0);
      add_ln_k<<<dim3(M), 256, 0, stream>>>(x, tbuf,
           ln_w + (size_t)(l * 3 + 2) * DD, ln_b + (size_t)(l * 3 + 2) * DD, xsH, xsL);
    }

    // logits = dec @ fc_out_w^T  (remap folded into C-write)
    gemmF(stream, xsH, xsL, wfcH, wfcL, out, VV, nullptr, M, VV, DD, 0, 1);
    softmax_d_k<<<dim3(BB * (SS - 1)), 256, 0, stream>>>(x, out + (size_t)BB * (SS - 1) * VV);
    return;
  }

  // ================= fallback: round-1 verified path =================
  add_pe_k<<<dim3((BB * SS * DD) / 256), 256, 0, stream>>>(te, x, nullptr, nullptr);

  for (int l = 0; l < NL; ++l) {
    gemm3(stream, x, DD,
          self_in_w + (size_t)l * 3 * DD * DD, DD,
          buf1, 3 * DD,
          self_in_b + (size_t)l * 3 * DD, M, 3 * DD, DD, 0, 0);
    gemm(stream, buf1, 3 * DD, (long long)SS * 3 * DD, HDD,
         buf1 + DD, 3 * DD, (long long)SS * 3 * DD, HDD, 0,
         sc, SS, (long long)NHH * SS * SS, (long long)SS * SS,
         nullptr, SS, SS, HDD, ishd, 0, 0, NHH, BB * NHH);
    softmax_rows_k<<<dim3(BB * NHH * SS), 256, 0, stream>>>(sc, SS, 1);
    gemm(stream, sc, SS, (long long)NHH * SS * SS, (long long)SS * SS,
         buf1 + 2 * DD, 3 * DD, (long long)SS * 3 * DD, HDD, 1,
         obuf, DD, (long long)SS * DD, HDD,
         nullptr, SS, HDD, SS, 1.f, 0, 0, NHH, BB * NHH);
    gemm3(stream, obuf, DD,
          self_out_w + (size_t)l * DD * DD, DD,
          tbuf, DD,
          self_out_b + (size_t)l * DD, M, DD, DD, 0, 0);
    add_ln_k<<<dim3(M), 256, 0, stream>>>(x, tbuf,
         ln_w + (size_t)(l * 3 + 0) * DD, ln_b + (size_t)(l * 3 + 0) * DD, nullptr, nullptr);

    float* qb  = buf1;
    float* kvb = buf1 + (size_t)M * DD;
    gemm3(stream, x, DD,
          cross_in_w + (size_t)l * 3 * DD * DD, DD,
          qb, DD,
          cross_in_b + (size_t)l * 3 * DD, M, DD, DD, 0, 0);
    gemm3(stream, fv, DD,
          cross_in_w + (size_t)l * 3 * DD * DD + (size_t)DD * DD, DD,
          kvb, 2 * DD,
          cross_in_b + (size_t)l * 3 * DD + DD, BB * NV, 2 * DD, DD, 0, 0);
    gemm(stream, qb, DD, (long long)SS * DD, HDD,
         kvb, 2 * DD, (long long)NV * 2 * DD, HDD, 0,
         sc, NV, (long long)NHH * SS * NV, (long long)SS * NV,
         nullptr, SS, NV, HDD, ishd, 0, 0, NHH, BB * NHH);
    softmax_rows_k<<<dim3(BB * NHH * SS), 256, 0, stream>>>(sc, NV, 0);
    gemm(stream, sc, NV, (long long)NHH * SS * NV, (long long)SS * NV,
         kvb + DD, 2 * DD, (long long)NV * 2 * DD, HDD, 1,
         obuf, DD, (long long)SS * DD, HDD,
         nullptr, SS, HDD, NV, 1.f, 0, 0, NHH, BB * NHH);
    gemm3(stream, obuf, DD,
          cross_out_w + (size_t)l * DD * DD, DD,
          tbuf, DD,
          cross_out_b + (size_t)l * DD, M, DD, DD, 0, 0);
    add_ln_k<<<dim3(M), 256, 0, stream>>>(x, tbuf,
         ln_w + (size_t)(l * 3 + 1) * DD, ln_b + (size_t)(l * 3 + 1) * DD, nullptr, nullptr);

    gemm3(stream, x, DD,
          lin1_w + (size_t)l * FFD * DD, DD,
          buf1, FFD,
          lin1_b + (size_t)l * FFD, M, FFD, DD, 1, 0);
    gemm3(stream, buf1, FFD,
          lin2_w + (size_t)l * DD * FFD, FFD,
          tbuf, DD,
          lin2_b + (size_t)l * DD, M, DD, FFD, 0, 0);
    add_ln_k<<<dim3(M), 256, 0, stream>>>(x, tbuf,
         ln_w + (size_t)(l * 3 + 2) * DD, ln_b + (size_t)(l * 3 + 2) * DD, nullptr, nullptr);
  }

  gemm3(stream, x, DD,
        fc_out_w, DD,
        out, VV,
        nullptr, BB * (SS - 1), VV, DD, 0, 1);
  softmax_d_k<<<dim3(BB * (SS - 1)), 256, 0, stream>>>(x, out + (size_t)BB * (SS - 1) * VV);
}